// Round 7
// baseline (238.347 us; speedup 1.0000x reference)
//
#include <hip/hip_runtime.h>
#include <stdint.h>

#define AS1 __attribute__((address_space(1)))
#define AS3 __attribute__((address_space(3)))

typedef __bf16 bf16x8 __attribute__((ext_vector_type(8)));
typedef float f32x4 __attribute__((ext_vector_type(4)));

constexpr int NB = 8;     // batches
constexpr int N  = 2048;  // nodes
constexpr int F  = 128;   // features (in == out)

__device__ __forceinline__ unsigned short bf16r(float f) {
    unsigned u = __float_as_uint(f);
    return (unsigned short)((u + 0x7FFFu + ((u >> 16) & 1u)) >> 16);
}
__device__ __forceinline__ float bf2f(unsigned short s) {
    return __uint_as_float(((unsigned)s) << 16);
}

// ---------------------------------------------------------------------------
// Wb2 element layout (MFMA-B-operand native):
//   byte(b, n, o) = b*N*F*2 + (n>>3)*2048 + o*16 + (n&7)*2
// ---------------------------------------------------------------------------

// K1 (fused): Wh = h @ W^T;  e = Wh @ a2;  p = exp(e);
//   p16 = bf16(p);  Wb2 = bf16(bf2f(p16) * Wh)
__global__ __launch_bounds__(256) void k1_wh(const float* __restrict__ h,
                                             const float* __restrict__ W,
                                             const float* __restrict__ a,
                                             unsigned short* __restrict__ Wb2,
                                             unsigned short* __restrict__ p16) {
    __shared__ float epart[2][64];

    const int tid  = threadIdx.x;
    const int lane = tid & 63, wid = tid >> 6;
    const int quad = lane >> 4, l15 = lane & 15;
    const int wm = wid >> 1, wn = wid & 1;
    const int m0 = blockIdx.x * 64;
    const int batch = m0 >> 11;
    const int nbase = m0 & 2047;

    f32x4 acc[2][4] = {};

#pragma unroll
    for (int kk = 0; kk < 4; ++kk) {
        const int k = kk * 32 + quad * 8;
        bf16x8 afr[2], bfr[4];
#pragma unroll
        for (int rt = 0; rt < 2; ++rt) {
            const float* src = h + (size_t)(m0 + wm * 32 + rt * 16 + l15) * F + k;
            float4 x0 = *(const float4*)src;
            float4 x1 = *(const float4*)(src + 4);
            afr[rt][0] = (__bf16)x0.x; afr[rt][1] = (__bf16)x0.y;
            afr[rt][2] = (__bf16)x0.z; afr[rt][3] = (__bf16)x0.w;
            afr[rt][4] = (__bf16)x1.x; afr[rt][5] = (__bf16)x1.y;
            afr[rt][6] = (__bf16)x1.z; afr[rt][7] = (__bf16)x1.w;
        }
#pragma unroll
        for (int ct = 0; ct < 4; ++ct) {
            const int o = wn * 64 + ct * 16 + l15;
            const float* src = W + (size_t)o * F + k;
            float4 x0 = *(const float4*)src;
            float4 x1 = *(const float4*)(src + 4);
            bfr[ct][0] = (__bf16)x0.x; bfr[ct][1] = (__bf16)x0.y;
            bfr[ct][2] = (__bf16)x0.z; bfr[ct][3] = (__bf16)x0.w;
            bfr[ct][4] = (__bf16)x1.x; bfr[ct][5] = (__bf16)x1.y;
            bfr[ct][6] = (__bf16)x1.z; bfr[ct][7] = (__bf16)x1.w;
        }
#pragma unroll
        for (int rt = 0; rt < 2; ++rt)
#pragma unroll
            for (int ct = 0; ct < 4; ++ct)
                acc[rt][ct] = __builtin_amdgcn_mfma_f32_16x16x32_bf16(
                    afr[rt], bfr[ct], acc[rt][ct], 0, 0, 0);
    }

    float a2v[4];
#pragma unroll
    for (int ct = 0; ct < 4; ++ct) a2v[ct] = a[F + wn * 64 + ct * 16 + l15];

    float ep[2][4];
#pragma unroll
    for (int rt = 0; rt < 2; ++rt)
#pragma unroll
        for (int g = 0; g < 4; ++g) {
            float s = 0.f;
#pragma unroll
            for (int ct = 0; ct < 4; ++ct) s += acc[rt][ct][g] * a2v[ct];
            ep[rt][g] = s;
        }
#pragma unroll
    for (int m = 1; m < 16; m <<= 1)
#pragma unroll
        for (int rt = 0; rt < 2; ++rt)
#pragma unroll
            for (int g = 0; g < 4; ++g)
                ep[rt][g] += __shfl_xor(ep[rt][g], m);

    if (l15 == 0)
#pragma unroll
        for (int rt = 0; rt < 2; ++rt)
#pragma unroll
            for (int g = 0; g < 4; ++g)
                epart[wn][wm * 32 + rt * 16 + quad * 4 + g] = ep[rt][g];
    __syncthreads();

#pragma unroll
    for (int rt = 0; rt < 2; ++rt)
#pragma unroll
        for (int ct = 0; ct < 4; ++ct) {
            const int o  = wn * 64 + ct * 16 + l15;
            const int r0 = wm * 32 + rt * 16 + quad * 4;
            const int n0 = nbase + r0;
            ushort4 v;
#pragma unroll
            for (int g = 0; g < 4; ++g) {
                const float e  = epart[0][r0 + g] + epart[1][r0 + g];
                const float pf = bf2f(bf16r(expf(e)));
                (&v.x)[g] = bf16r(pf * acc[rt][ct][g]);
            }
            size_t off = (size_t)batch * N * F + (size_t)(n0 >> 3) * 1024 + o * 8 + (n0 & 7);
            *(ushort4*)&Wb2[off] = v;
        }

    if (tid < 64) {
        const float e = epart[0][tid] + epart[1][tid];
        p16[batch * N + nbase + tid] = bf16r(expf(e));
    }
}

// K3: out[b][i][o] = (sum_j adj[b][i][j] * Wb2[j][o]) / (sum_j adj * p[j])
// AITER-style K-loop: raw s_barrier + exact hand vmcnt; staging prefetch
// (asm global_load_lds_dwordx4, M0 LDS base) survives the barrier.
// Tile 16(i) x 128(o), 4 waves (o-slice 32/wave), BK=64, 3 LDS buffers.
// Per iter (chunk c): s_barrier | 6 asm B/p loads(c) | 1 asm stage(c+2) |
// s_waitcnt vmcnt(1)  -> drains S(c+1)+B(c), leaves S(c+2) in flight.
__global__ __launch_bounds__(256) void k3_attn(const float* __restrict__ adj,
                                               const unsigned short* __restrict__ Wb2,
                                               const unsigned short* __restrict__ p16,
                                               float* __restrict__ out) {
    __shared__ __align__(16) float At[3][16 * 64];   // 4 KB per buffer

    const int tid  = threadIdx.x;
    const int lane = tid & 63, wid = tid >> 6;
    const int quad = lane >> 4, l15 = lane & 15;
    const int b  = blockIdx.x & 7;               // XCD-pin: batch -> one XCD's L2
    const int i0 = (blockIdx.x >> 3) * 16;

    // staging source: lane covers row ri = wid*4 + (lane>>4), 16B slot
    // lslot = lane&15 holds global 16B-chunk lslot^ri (XOR swizzle).
    const int ri = wid * 4 + (lane >> 4);
    const int lslot = lane & 15;
    const char* aSt = (const char*)adj
        + ((size_t)b * N * N + (size_t)(i0 + ri) * N + ((lslot ^ ri) << 2)) * 4;
    // staging LDS dest (wave-uniform), one per buffer slot
    unsigned lds0 = (unsigned)(size_t)(AS3 char*)((char*)&At[0][0] + wid * 1024);
    lds0 = __builtin_amdgcn_readfirstlane(lds0);
    const unsigned ldsA[3] = { lds0, lds0 + 4096u, lds0 + 8192u };

    const char* WbB = (const char*)Wb2 + (size_t)b * N * F * 2
                    + wid * 512 + l15 * 16;      // + (c*8+ks*4+quad)*2048 + ct*256
    const char* pB  = (const char*)p16 + (size_t)b * N * 2 + quad * 16;

    f32x4 acc[2] = {};
    f32x4 dacc = {};

#define STAGE(C, WS)                                                          \
    asm volatile("s_mov_b32 m0, %0\n\t"                                       \
                 "global_load_lds_dwordx4 %1, off"                            \
                 :: "s"(ldsA[WS]), "v"((uint64_t)(aSt + (size_t)(C) * 256))   \
                 : "memory")

#define BODY(C, RS, WS, DO_STAGE, VMSTR) do {                                 \
    asm volatile("s_barrier" ::: "memory");                                   \
    f32x4 b00, b01, b10, b11, p0, p1;                                         \
    {                                                                         \
        const char* bp0 = WbB + ((size_t)(C) * 8 + quad) * 2048;              \
        const char* bp1 = bp0 + 4 * 2048;                                     \
        asm volatile(                                                         \
            "global_load_dwordx4 %0, %6, off\n\t"                             \
            "global_load_dwordx4 %1, %7, off\n\t"                             \
            "global_load_dwordx4 %2, %8, off\n\t"                             \
            "global_load_dwordx4 %3, %9, off\n\t"                             \
            "global_load_dwordx4 %4, %10, off\n\t"                            \
            "global_load_dwordx4 %5, %11, off"                                \
            : "=&v"(b00), "=&v"(b01), "=&v"(b10), "=&v"(b11),                 \
              "=&v"(p0), "=&v"(p1)                                            \
            : "v"((uint64_t)bp0), "v"((uint64_t)(bp0 + 256)),                 \
              "v"((uint64_t)bp1), "v"((uint64_t)(bp1 + 256)),                 \
              "v"((uint64_t)(pB + (size_t)(C) * 128)),                        \
              "v"((uint64_t)(pB + (size_t)(C) * 128 + 64))                    \
            : "memory");                                                      \
    }                                                                         \
    if (DO_STAGE) STAGE((C) + 2, WS);                                         \
    asm volatile("s_waitcnt " VMSTR                                           \
        : "+v"(b00), "+v"(b01), "+v"(b10), "+v"(b11), "+v"(p0), "+v"(p1)      \
        :: "memory");                                                         \
    const char* rowb = (const char*)&At[RS][0] + l15 * 256;                   \
    _Pragma("unroll")                                                         \
    for (int ks = 0; ks < 2; ++ks) {                                          \
        const int g0 = ks * 8 + quad * 2;                                     \
        f32x4 x0 = *(const f32x4*)(rowb + ((g0 ^ l15) << 4));                 \
        f32x4 x1 = *(const f32x4*)(rowb + (((g0 + 1) ^ l15) << 4));           \
        bf16x8 af;                                                            \
        af[0] = (__bf16)x0[0]; af[1] = (__bf16)x0[1];                         \
        af[2] = (__bf16)x0[2]; af[3] = (__bf16)x0[3];                         \
        af[4] = (__bf16)x1[0]; af[5] = (__bf16)x1[1];                         \
        af[6] = (__bf16)x1[2]; af[7] = (__bf16)x1[3];                         \
        acc[0] = __builtin_amdgcn_mfma_f32_16x16x32_bf16(                     \
            af, __builtin_bit_cast(bf16x8, ks ? b10 : b00), acc[0], 0, 0, 0); \
        acc[1] = __builtin_amdgcn_mfma_f32_16x16x32_bf16(                     \
            af, __builtin_bit_cast(bf16x8, ks ? b11 : b01), acc[1], 0, 0, 0); \
        dacc   = __builtin_amdgcn_mfma_f32_16x16x32_bf16(                     \
            af, __builtin_bit_cast(bf16x8, ks ? p1 : p0), dacc, 0, 0, 0);     \
    }                                                                         \
} while (0)

    // prologue: chunks 0,1 in flight
    STAGE(0, 0);
    STAGE(1, 1);

    for (int c = 0; c < 30; c += 3) {
        BODY(c + 0, 0, 2, 1, "vmcnt(1)");
        BODY(c + 1, 1, 0, 1, "vmcnt(1)");
        BODY(c + 2, 2, 1, 1, "vmcnt(1)");
    }
    BODY(30, 0, 0, 0, "vmcnt(0)");
    BODY(31, 1, 0, 0, "vmcnt(0)");

#undef STAGE
#undef BODY

    // dacc reg g = denom for row quad*4+g — same row mapping as acc.
    float inv[4];
#pragma unroll
    for (int g = 0; g < 4; ++g) inv[g] = 1.0f / dacc[g];

    float* ob = out + (size_t)b * N * F;
#pragma unroll
    for (int ct = 0; ct < 2; ++ct) {
        const int o = wid * 32 + ct * 16 + l15;
#pragma unroll
        for (int g = 0; g < 4; ++g) {
            const int i = i0 + quad * 4 + g;
            ob[(size_t)i * F + o] = acc[ct][g] * inv[g];
        }
    }
}

// ---------------------------------------------------------------------------
extern "C" void kernel_launch(void* const* d_in, const int* in_sizes, int n_in,
                              void* d_out, int out_size, void* d_ws, size_t ws_size,
                              hipStream_t stream) {
    const float* h   = (const float*)d_in[0];
    const float* adj = (const float*)d_in[1];
    const float* W   = (const float*)d_in[2];
    const float* a   = (const float*)d_in[3];
    float* out = (float*)d_out;

    unsigned short* Wb2 = (unsigned short*)d_ws;                          // 4 MB
    unsigned short* p16 = (unsigned short*)((char*)d_ws + (4u << 20));    // 32 KB

    k1_wh<<<NB * N / 64, 256, 0, stream>>>(h, W, a, Wb2, p16);
    k3_attn<<<NB * (N / 16), 256, 0, stream>>>(adj, Wb2, p16, out);
}

// Round 9
// 220.267 us; speedup vs baseline: 1.0821x; 1.0821x over previous
//
#include <hip/hip_runtime.h>
#include <stdint.h>

#define AS1 __attribute__((address_space(1)))
#define AS3 __attribute__((address_space(3)))

typedef __bf16 bf16x8 __attribute__((ext_vector_type(8)));
typedef float f32x4 __attribute__((ext_vector_type(4)));

constexpr int NB = 8;     // batches
constexpr int N  = 2048;  // nodes
constexpr int F  = 128;   // features (in == out)

__device__ __forceinline__ unsigned short bf16r(float f) {
    unsigned u = __float_as_uint(f);
    return (unsigned short)((u + 0x7FFFu + ((u >> 16) & 1u)) >> 16);
}
__device__ __forceinline__ float bf2f(unsigned short s) {
    return __uint_as_float(((unsigned)s) << 16);
}

// ---------------------------------------------------------------------------
// Wb2 element layout (MFMA-B-operand native, linear in k-chunks):
//   byte(b, n, o) = b*N*F*2 + (n>>3)*2048 + o*16 + (n&7)*2
// A BK=64 chunk c of batch b = the contiguous 16384 B at  b*N*F*2 + c*16384.
// (R8 bug: staged with stride 32768 — wrong nodes for every chunk. Fixed.)
// ---------------------------------------------------------------------------

// K1 (fused): Wh = h @ W^T;  e = Wh @ a2;  p = exp(e);
//   p16 = bf16(p);  Wb2 = bf16(bf2f(p16) * Wh)
__global__ __launch_bounds__(256) void k1_wh(const float* __restrict__ h,
                                             const float* __restrict__ W,
                                             const float* __restrict__ a,
                                             unsigned short* __restrict__ Wb2,
                                             unsigned short* __restrict__ p16) {
    __shared__ float epart[2][64];

    const int tid  = threadIdx.x;
    const int lane = tid & 63, wid = tid >> 6;
    const int quad = lane >> 4, l15 = lane & 15;
    const int wm = wid >> 1, wn = wid & 1;
    const int m0 = blockIdx.x * 64;
    const int batch = m0 >> 11;
    const int nbase = m0 & 2047;

    f32x4 acc[2][4] = {};

#pragma unroll
    for (int kk = 0; kk < 4; ++kk) {
        const int k = kk * 32 + quad * 8;
        bf16x8 afr[2], bfr[4];
#pragma unroll
        for (int rt = 0; rt < 2; ++rt) {
            const float* src = h + (size_t)(m0 + wm * 32 + rt * 16 + l15) * F + k;
            float4 x0 = *(const float4*)src;
            float4 x1 = *(const float4*)(src + 4);
            afr[rt][0] = (__bf16)x0.x; afr[rt][1] = (__bf16)x0.y;
            afr[rt][2] = (__bf16)x0.z; afr[rt][3] = (__bf16)x0.w;
            afr[rt][4] = (__bf16)x1.x; afr[rt][5] = (__bf16)x1.y;
            afr[rt][6] = (__bf16)x1.z; afr[rt][7] = (__bf16)x1.w;
        }
#pragma unroll
        for (int ct = 0; ct < 4; ++ct) {
            const int o = wn * 64 + ct * 16 + l15;
            const float* src = W + (size_t)o * F + k;
            float4 x0 = *(const float4*)src;
            float4 x1 = *(const float4*)(src + 4);
            bfr[ct][0] = (__bf16)x0.x; bfr[ct][1] = (__bf16)x0.y;
            bfr[ct][2] = (__bf16)x0.z; bfr[ct][3] = (__bf16)x0.w;
            bfr[ct][4] = (__bf16)x1.x; bfr[ct][5] = (__bf16)x1.y;
            bfr[ct][6] = (__bf16)x1.z; bfr[ct][7] = (__bf16)x1.w;
        }
#pragma unroll
        for (int rt = 0; rt < 2; ++rt)
#pragma unroll
            for (int ct = 0; ct < 4; ++ct)
                acc[rt][ct] = __builtin_amdgcn_mfma_f32_16x16x32_bf16(
                    afr[rt], bfr[ct], acc[rt][ct], 0, 0, 0);
    }

    float a2v[4];
#pragma unroll
    for (int ct = 0; ct < 4; ++ct) a2v[ct] = a[F + wn * 64 + ct * 16 + l15];

    float ep[2][4];
#pragma unroll
    for (int rt = 0; rt < 2; ++rt)
#pragma unroll
        for (int g = 0; g < 4; ++g) {
            float s = 0.f;
#pragma unroll
            for (int ct = 0; ct < 4; ++ct) s += acc[rt][ct][g] * a2v[ct];
            ep[rt][g] = s;
        }
#pragma unroll
    for (int m = 1; m < 16; m <<= 1)
#pragma unroll
        for (int rt = 0; rt < 2; ++rt)
#pragma unroll
            for (int g = 0; g < 4; ++g)
                ep[rt][g] += __shfl_xor(ep[rt][g], m);

    if (l15 == 0)
#pragma unroll
        for (int rt = 0; rt < 2; ++rt)
#pragma unroll
            for (int g = 0; g < 4; ++g)
                epart[wn][wm * 32 + rt * 16 + quad * 4 + g] = ep[rt][g];
    __syncthreads();

#pragma unroll
    for (int rt = 0; rt < 2; ++rt)
#pragma unroll
        for (int ct = 0; ct < 4; ++ct) {
            const int o  = wn * 64 + ct * 16 + l15;
            const int r0 = wm * 32 + rt * 16 + quad * 4;
            const int n0 = nbase + r0;
            ushort4 v;
#pragma unroll
            for (int g = 0; g < 4; ++g) {
                const float e  = epart[0][r0 + g] + epart[1][r0 + g];
                const float pf = bf2f(bf16r(expf(e)));
                (&v.x)[g] = bf16r(pf * acc[rt][ct][g]);
            }
            size_t off = (size_t)batch * N * F + (size_t)(n0 >> 3) * 1024 + o * 8 + (n0 & 7);
            *(ushort4*)&Wb2[off] = v;
        }

    if (tid < 64) {
        const float e = epart[0][tid] + epart[1][tid];
        p16[batch * N + nbase + tid] = bf16r(expf(e));
    }
}

// K3: out[b][i][o] = (sum_j adj[b][i][j] * Wb2[j][o]) / (sum_j adj * p[j])
// BOTH operands staged via global_load_lds (B's blocked layout is linear ->
// straight copy). Tile 16(i) x 128(o), 4 waves (o-slice 32/wave), BK=64,
// dbuf A (4 KB, XOR-swizzle) + dbuf B (16 KB, linear) = 40 KB LDS ->
// 4 blocks/CU at grid 1024. R5-proven cadence: barrier | stage(c+1) |
// compute(c). In-body VMEM = 2 tiny quad-uniform p-loads only.
// XCD-pin: batch = blockIdx&7 keeps each batch's 512 KB Wb2 in one L2.
__global__ __launch_bounds__(256) void k3_attn(const float* __restrict__ adj,
                                               const unsigned short* __restrict__ Wb2,
                                               const unsigned short* __restrict__ p16,
                                               float* __restrict__ out) {
    __shared__ __align__(16) float          At[2][16 * 64];    // 4 KB each
    __shared__ __align__(16) unsigned short Bt[2][8 * 1024];   // 16 KB each

    const int tid  = threadIdx.x;
    const int lane = tid & 63, wid = tid >> 6;
    const int quad = lane >> 4, l15 = lane & 15;
    const int b  = blockIdx.x & 7;
    const int i0 = (blockIdx.x >> 3) * 16;

    // A staging: 1 instr/wave covers rows ri = wid*4 .. +3 (256 B each).
    // Slot lslot in row ri holds global 16B-chunk lslot^ri.
    const int ri = wid * 4 + (lane >> 4);
    const int lslot = lane & 15;
    const float* aSrc = adj + (size_t)b * N * N + (size_t)(i0 + ri) * N
                      + ((lslot ^ ri) << 2);
    // B staging: linear copy, 4 instr/wave (wave covers bytes wid*4K..+4K).
    const char* bSrc = (const char*)Wb2 + (size_t)b * N * F * 2
                     + (size_t)wid * 4096 + lane * 16;
    const unsigned short* pb = p16 + b * N;

    auto stage = [&](int buf, int c) {
        __builtin_amdgcn_global_load_lds((const AS1 void*)(aSrc + c * 64),
            (AS3 void*)((char*)&At[buf][0] + wid * 1024), 16, 0, 0);
#pragma unroll
        for (int s = 0; s < 4; ++s)
            __builtin_amdgcn_global_load_lds(
                (const AS1 void*)(bSrc + (size_t)c * 16384 + s * 1024),
                (AS3 void*)((char*)&Bt[buf][0] + wid * 4096 + s * 1024), 16, 0, 0);
    };

    f32x4 acc[2] = {};
    f32x4 dacc = {};

    stage(0, 0);

    for (int c = 0; c < 32; ++c) {
        const int cur = c & 1;
        __syncthreads();              // drains stage(c); frees other buffer
        if (c + 1 < 32) stage(cur ^ 1, c + 1);

#pragma unroll
        for (int ks = 0; ks < 2; ++ks) {
            // A frag: row l15, global chunks g0 = ks*8+quad*2, g0+1
            const char* rowb = (const char*)&At[cur][0] + l15 * 256;
            const int g0 = ks * 8 + quad * 2;
            f32x4 x0 = *(const f32x4*)(rowb + ((g0 ^ l15) << 4));
            f32x4 x1 = *(const f32x4*)(rowb + (((g0 + 1) ^ l15) << 4));
            // B frags from LDS (linear image): kk8 = ks*4+quad, o = wid*32+ct*16+l15
            const char* bb = (const char*)&Bt[cur][0]
                           + (ks * 4 + quad) * 2048 + wid * 512 + l15 * 16;
            bf16x8 b0 = *(const bf16x8*)bb;
            bf16x8 b1 = *(const bf16x8*)(bb + 256);
            bf16x8 pv = *(const bf16x8*)(pb + c * 64 + ks * 32 + quad * 8);

            bf16x8 af;   // adj in {0,1}: cvt exact; p folded into B
            af[0] = (__bf16)x0[0]; af[1] = (__bf16)x0[1];
            af[2] = (__bf16)x0[2]; af[3] = (__bf16)x0[3];
            af[4] = (__bf16)x1[0]; af[5] = (__bf16)x1[1];
            af[6] = (__bf16)x1[2]; af[7] = (__bf16)x1[3];

            acc[0] = __builtin_amdgcn_mfma_f32_16x16x32_bf16(af, b0, acc[0], 0, 0, 0);
            acc[1] = __builtin_amdgcn_mfma_f32_16x16x32_bf16(af, b1, acc[1], 0, 0, 0);
            dacc   = __builtin_amdgcn_mfma_f32_16x16x32_bf16(af, pv, dacc, 0, 0, 0);
        }
    }

    // dacc reg g = denom for row quad*4+g — same row mapping as acc.
    float inv[4];
#pragma unroll
    for (int g = 0; g < 4; ++g) inv[g] = 1.0f / dacc[g];

    float* ob = out + (size_t)b * N * F;
#pragma unroll
    for (int ct = 0; ct < 2; ++ct) {
        const int o = wid * 32 + ct * 16 + l15;
#pragma unroll
        for (int g = 0; g < 4; ++g) {
            const int i = i0 + quad * 4 + g;
            ob[(size_t)i * F + o] = acc[ct][g] * inv[g];
        }
    }
}

// ---------------------------------------------------------------------------
extern "C" void kernel_launch(void* const* d_in, const int* in_sizes, int n_in,
                              void* d_out, int out_size, void* d_ws, size_t ws_size,
                              hipStream_t stream) {
    const float* h   = (const float*)d_in[0];
    const float* adj = (const float*)d_in[1];
    const float* W   = (const float*)d_in[2];
    const float* a   = (const float*)d_in[3];
    float* out = (float*)d_out;

    unsigned short* Wb2 = (unsigned short*)d_ws;                          // 4 MB
    unsigned short* p16 = (unsigned short*)((char*)d_ws + (4u << 20));    // 32 KB

    k1_wh<<<NB * N / 64, 256, 0, stream>>>(h, W, a, Wb2, p16);
    k3_attn<<<NB * (N / 16), 256, 0, stream>>>(adj, Wb2, p16, out);
}